// Round 7
// baseline (434.766 us; speedup 1.0000x reference)
//
#include <hip/hip_runtime.h>
#include <hip/hip_bf16.h>
#include <math.h>

// Problem constants
#define Bz    4
#define Cch   192
#define Nn    4096
#define BN    16384      // Bz*Nn
#define Ecnt  262144     // Bz*Nn*16
#define COUT  384
#define CAP   64         // max degree capacity (random 262144->16384 bins: max ~34)
#define GRID  1024       // co-resident: __launch_bounds__(256,4) -> 4 blocks/CU x 256 CU

typedef __attribute__((ext_vector_type(8))) short short8;
typedef __attribute__((ext_vector_type(4))) float floatx4;

__device__ __forceinline__ void gload_lds16(const void* g, void* l) {
    __builtin_amdgcn_global_load_lds(
        (const __attribute__((address_space(1))) unsigned int*)g,
        (__attribute__((address_space(3))) unsigned int*)l, 16, 0, 0);
}

__device__ __forceinline__ float b2f(unsigned short u) {
    union { unsigned int i; float f; } z; z.i = ((unsigned int)u) << 16; return z.f;
}
__device__ __forceinline__ unsigned short f2b(float f) {
    __hip_bfloat16 h = __float2bfloat16(f);
    return *(unsigned short*)&h;
}

// One-shot grid barrier (counters pre-zeroed by host memset; one counter per use).
// All GRID blocks are co-resident by construction, so spinning cannot deadlock.
__device__ __forceinline__ void grid_barrier(int* __restrict__ bar, int idx) {
    __syncthreads();
    if (threadIdx.x == 0) {
        __threadfence();   // agent-scope release of all prior writes
        int* c = bar + idx;
        __hip_atomic_fetch_add(c, 1, __ATOMIC_ACQ_REL, __HIP_MEMORY_SCOPE_AGENT);
        while (__hip_atomic_load(c, __ATOMIC_ACQUIRE, __HIP_MEMORY_SCOPE_AGENT) < GRID) {}
        __threadfence();
    }
    __syncthreads();
}

// ---------------------------------------------------------------------------
// Monolithic: P1 (transpose + W-deint + edge fill) | barrier | P2 (agg) |
// barrier | P3 (64x64 MFMA gemm). All phase bodies identical to the verified
// round-4 kernels; only the outer grid-stride mapping changed.
__global__ __launch_bounds__(256, 4) void mono_kernel(
    const float* __restrict__ x, const int* __restrict__ ew,
    const float* __restrict__ W, const float* __restrict__ bias,
    __hip_bfloat16* __restrict__ xb, __hip_bfloat16* __restrict__ aggb,
    __hip_bfloat16* __restrict__ Wx, __hip_bfloat16* __restrict__ Wa,
    int* __restrict__ deg, int* __restrict__ slots, int* __restrict__ bar,
    float* __restrict__ out) {
    __shared__ float tileT[32][33];   // 4224 B (P1 transpose)
    __shared__ short As[64 * 32];     // 4096 B (P3)
    __shared__ short Bs[64 * 32];     // 4096 B (P3)
    __shared__ int s_is64;
    int t = threadIdx.x;
    int bid = blockIdx.x;
    int lane = t & 63, wave = t >> 6;

    // --- detect int64 vs int32 edge layout (once per block, 2KB L2-hit) ---
    if (t == 0) s_is64 = 1;
    __syncthreads();
    if (((const unsigned int*)ew)[2 * t + 1] != 0u) atomicAnd(&s_is64, 0);
    __syncthreads();
    int is64 = s_is64;

    // ---- P1: units [0,3072) transpose; [3072,3360) W deint; [3360,3872) fill ----
    for (int u = bid; u < 3872; u += GRID) {
        if (u < 3072) {
            int b = u / 768;
            int r = u - b * 768;
            int c0 = (r >> 7) * 32;
            int n0 = (r & 127) * 32;
            int tx = t & 31, ty = t >> 5;
            __syncthreads();
            for (int i = ty; i < 32; i += 8)
                tileT[i][tx] = x[((size_t)(b * Cch + c0 + i)) * Nn + n0 + tx];
            __syncthreads();
            for (int i = ty; i < 32; i += 8)
                xb[((size_t)(b * Nn + n0 + i)) * Cch + c0 + tx] =
                    __float2bfloat16(tileT[tx][i]);
        } else if (u < 3360) {
            int i = (u - 3072) * 256 + t;    // exactly COUT*Cch = 73728
            int o = i / Cch, c = i - o * Cch;
            Wx[i] = __float2bfloat16(W[o * 2 * Cch + 2 * c]);
            Wa[i] = __float2bfloat16(W[o * 2 * Cch + 2 * c + 1]);
        } else {
            int te = (u - 3360) * 256 + t;   // [0, Ecnt/2)
            int d0, d1, s0, s1;
            if (is64) {  // dst e -> word 2e; src e -> word 2*Ecnt+2e
                int4 dv = *(const int4*)&ew[4 * te];
                int4 sv = *(const int4*)&ew[2 * Ecnt + 4 * te];
                d0 = dv.x; d1 = dv.z; s0 = sv.x; s1 = sv.z;
            } else {
                int2 dv = *(const int2*)&ew[2 * te];
                int2 sv = *(const int2*)&ew[Ecnt + 2 * te];
                d0 = dv.x; d1 = dv.y; s0 = sv.x; s1 = sv.y;
            }
            int p0 = atomicAdd(&deg[d0], 1); if (p0 < CAP) slots[(d0 << 6) + p0] = s0;
            int p1 = atomicAdd(&deg[d1], 1); if (p1 < CAP) slots[(d1 << 6) + p1] = s1;
        }
    }
    grid_barrier(bar, 0);

    // ---- P2: agg. One wave per node, 4 nodes per unit, 4096 units. ----
    {
        const unsigned short* xbu = (const unsigned short*)xb;
        int act = lane < 48;
        int cb = lane * 4;
        for (int u = bid; u < 4096; u += GRID) {
            int node = (u << 2) + wave;
            int d = deg[node]; if (d > CAP) d = CAP;
            int nbrval = 0;
            if (lane < d) nbrval = slots[(node << 6) + lane];
            float m0 = -INFINITY, m1 = -INFINITY, m2 = -INFINITY, m3 = -INFINITY;
            int k = 0;
            for (; k + 4 <= d; k += 4) {
                int s0 = __shfl(nbrval, k);
                int s1 = __shfl(nbrval, k + 1);
                int s2 = __shfl(nbrval, k + 2);
                int s3 = __shfl(nbrval, k + 3);
                if (act) {
                    ushort4 v0 = *(const ushort4*)&xbu[s0 * Cch + cb];
                    ushort4 v1 = *(const ushort4*)&xbu[s1 * Cch + cb];
                    ushort4 v2 = *(const ushort4*)&xbu[s2 * Cch + cb];
                    ushort4 v3 = *(const ushort4*)&xbu[s3 * Cch + cb];
                    m0 = fmaxf(fmaxf(m0, b2f(v0.x)), fmaxf(fmaxf(b2f(v1.x), b2f(v2.x)), b2f(v3.x)));
                    m1 = fmaxf(fmaxf(m1, b2f(v0.y)), fmaxf(fmaxf(b2f(v1.y), b2f(v2.y)), b2f(v3.y)));
                    m2 = fmaxf(fmaxf(m2, b2f(v0.z)), fmaxf(fmaxf(b2f(v1.z), b2f(v2.z)), b2f(v3.z)));
                    m3 = fmaxf(fmaxf(m3, b2f(v0.w)), fmaxf(fmaxf(b2f(v1.w), b2f(v2.w)), b2f(v3.w)));
                }
            }
            for (; k < d; k++) {
                int s = __shfl(nbrval, k);
                if (act) {
                    ushort4 v = *(const ushort4*)&xbu[s * Cch + cb];
                    m0 = fmaxf(m0, b2f(v.x)); m1 = fmaxf(m1, b2f(v.y));
                    m2 = fmaxf(m2, b2f(v.z)); m3 = fmaxf(m3, b2f(v.w));
                }
            }
            if (act) {
                ushort4 xv = *(const ushort4*)&xbu[node * Cch + cb];
                ushort4 o4;
                o4.x = (d > 0) ? f2b(m0 - b2f(xv.x)) : 0;
                o4.y = (d > 0) ? f2b(m1 - b2f(xv.y)) : 0;
                o4.z = (d > 0) ? f2b(m2 - b2f(xv.z)) : 0;
                o4.w = (d > 0) ? f2b(m3 - b2f(xv.w)) : 0;
                *(ushort4*)&((unsigned short*)aggb)[node * Cch + cb] = o4;
            }
        }
    }
    grid_barrier(bar, 1);

    // ---- P3: gemm, 64x64 tiles, 1536 units ----
    {
        int quad = lane >> 4, lrow = lane & 15;
        int wm = wave & 1, wn = wave >> 1;
        int srow = t >> 2;             // 4 threads per row
        int koff = (t & 3) * 8;        // 8 bf16 = 16 B each
        const __hip_bfloat16* Asrc[2] = {xb, aggb};
        const __hip_bfloat16* Bsrc[2] = {Wx, Wa};

        for (int u = bid; u < 1536; u += GRID) {
            int node0 = (u & 255) * 64;
            int o0    = (u >> 8) * 64;
            floatx4 acc[2][2] = {};
            for (int seg = 0; seg < 2; seg++) {
                const __hip_bfloat16* a_g = Asrc[seg] + (size_t)(node0 + srow) * Cch + koff;
                const __hip_bfloat16* b_g = Bsrc[seg] + (size_t)(o0 + srow) * Cch + koff;
                for (int kt = 0; kt < Cch; kt += 32) {
                    __syncthreads();
                    gload_lds16(a_g + kt, &As[t * 8]);
                    gload_lds16(b_g + kt, &Bs[t * 8]);
                    __syncthreads();
                    short8 af0 = *(const short8*)&As[(wm * 32 + lrow) * 32 + quad * 8];
                    short8 af1 = *(const short8*)&As[(wm * 32 + 16 + lrow) * 32 + quad * 8];
                    short8 bf0 = *(const short8*)&Bs[(wn * 32 + lrow) * 32 + quad * 8];
                    short8 bf1 = *(const short8*)&Bs[(wn * 32 + 16 + lrow) * 32 + quad * 8];
                    acc[0][0] = __builtin_amdgcn_mfma_f32_16x16x32_bf16(bf0, af0, acc[0][0], 0, 0, 0);
                    acc[1][0] = __builtin_amdgcn_mfma_f32_16x16x32_bf16(bf0, af1, acc[1][0], 0, 0, 0);
                    acc[0][1] = __builtin_amdgcn_mfma_f32_16x16x32_bf16(bf1, af0, acc[0][1], 0, 0, 0);
                    acc[1][1] = __builtin_amdgcn_mfma_f32_16x16x32_bf16(bf1, af1, acc[1][1], 0, 0, 0);
                }
            }
            // D layout: col(lane&15)=node, row(quad*4+r)=o
#pragma unroll
            for (int im = 0; im < 2; im++) {
                int node = node0 + wm * 32 + im * 16 + lrow;
                int b = node >> 12, n = node & 4095;
#pragma unroll
                for (int in = 0; in < 2; in++) {
                    int ob = o0 + wn * 32 + in * 16 + quad * 4;
#pragma unroll
                    for (int r = 0; r < 4; r++) {
                        int o = ob + r;
                        float v = acc[im][in][r] + bias[o];
                        out[((size_t)(b * COUT + o)) * Nn + n] = fmaxf(v, 0.0f);
                    }
                }
            }
        }
    }
}

// ---------------------------------------------------------------------------
extern "C" void kernel_launch(void* const* d_in, const int* in_sizes, int n_in,
                              void* d_out, int out_size, void* d_ws, size_t ws_size,
                              hipStream_t stream) {
    const float* x    = (const float*)d_in[0];
    const int*   ew   = (const int*)d_in[1];
    const float* W    = (const float*)d_in[2];
    const float* bias = (const float*)d_in[3];
    float* out        = (float*)d_out;

    char* ws = (char*)d_ws;
    __hip_bfloat16* xb   = (__hip_bfloat16*)ws;                       // 6291456 B
    __hip_bfloat16* aggb = (__hip_bfloat16*)(ws + 6291456);           // 6291456 B
    __hip_bfloat16* Wx   = (__hip_bfloat16*)(ws + 12582912);          // 147456 B
    __hip_bfloat16* Wa   = (__hip_bfloat16*)(ws + 12730368);          // 147456 B
    int* deg   = (int*)(ws + 12877824);                               // 65536 B
    int* bar   = (int*)(ws + 12943360);                               // 64 B (2 counters)
    int* slots = (int*)(ws + 12943424);                               // 4194304 B

    // zero deg + barrier counters in one async memset (graph-safe)
    hipMemsetAsync(deg, 0, 65536 + 64, stream);
    mono_kernel<<<GRID, 256, 0, stream>>>(x, ew, W, bias, xb, aggb, Wx, Wa,
                                          deg, slots, bar, out);
}

// Round 8
// 115.439 us; speedup vs baseline: 3.7662x; 3.7662x over previous
//
#include <hip/hip_runtime.h>
#include <hip/hip_bf16.h>
#include <math.h>

// Problem constants
#define Bz    4
#define Cch   192
#define Nn    4096
#define BN    16384      // Bz*Nn
#define Ecnt  262144     // Bz*Nn*16
#define COUT  384
#define CAP   64         // max degree capacity (random 262144->16384 bins: max ~34)

typedef __attribute__((ext_vector_type(8))) short short8;
typedef __attribute__((ext_vector_type(4))) float floatx4;

__device__ __forceinline__ void gload_lds16(const void* g, void* l) {
    __builtin_amdgcn_global_load_lds(
        (const __attribute__((address_space(1))) unsigned int*)g,
        (__attribute__((address_space(3))) unsigned int*)l, 16, 0, 0);
}

__device__ __forceinline__ float b2f(unsigned short u) {
    union { unsigned int i; float f; } z; z.i = ((unsigned int)u) << 16; return z.f;
}
__device__ __forceinline__ unsigned short f2b(float f) {
    __hip_bfloat16 h = __float2bfloat16(f);
    return *(unsigned short*)&h;
}

// ---------------------------------------------------------------------------
// Fused prep (round-4 proven): [0,3072) transpose x->xb bf16; [3072,3360) W
// deinterleave; [3360,3424) zero deg; [3424] int64-vs-int32 detect.
__global__ __launch_bounds__(256) void prep_kernel(
    const float* __restrict__ x, const unsigned int* __restrict__ ew,
    const float* __restrict__ W, __hip_bfloat16* __restrict__ xb,
    __hip_bfloat16* __restrict__ Wx, __hip_bfloat16* __restrict__ Wa,
    int* __restrict__ deg, int* __restrict__ flag) {
    int bid = blockIdx.x;
    if (bid < 3072) {
        __shared__ float tile[32][33];
        int b = bid / 768;
        int r = bid - b * 768;
        int c0 = (r >> 7) * 32;         // 6 c-tiles
        int n0 = (r & 127) * 32;        // 128 n-tiles
        int tx = threadIdx.x & 31, ty = threadIdx.x >> 5;
        for (int i = ty; i < 32; i += 8)
            tile[i][tx] = x[((size_t)(b * Cch + c0 + i)) * Nn + n0 + tx];
        __syncthreads();
        for (int i = ty; i < 32; i += 8)
            xb[((size_t)(b * Nn + n0 + i)) * Cch + c0 + tx] =
                __float2bfloat16(tile[tx][i]);
    } else if (bid < 3360) {
        int i = (bid - 3072) * 256 + threadIdx.x;   // exactly COUT*Cch = 73728
        int o = i / Cch, c = i - o * Cch;
        Wx[i] = __float2bfloat16(W[o * 2 * Cch + 2 * c]);
        Wa[i] = __float2bfloat16(W[o * 2 * Cch + 2 * c + 1]);
    } else if (bid < 3424) {
        deg[(bid - 3360) * 256 + threadIdx.x] = 0;  // exactly BN = 16384
    } else {
        __shared__ int s;
        if (threadIdx.x == 0) s = 1;
        __syncthreads();
        if (ew[2 * threadIdx.x + 1] != 0u) atomicAnd(&s, 0);
        __syncthreads();
        if (threadIdx.x == 0) *flag = s;
    }
}

// ---------------------------------------------------------------------------
// Count degree + place src into fixed-capacity slot table. 2 edges/thread.
__global__ __launch_bounds__(256) void fill_kernel(
    const int* __restrict__ ew, const int* __restrict__ flag,
    int* __restrict__ deg, int* __restrict__ slots) {
    int t = blockIdx.x * 256 + threadIdx.x;   // [0, Ecnt/2)
    int d0, d1, s0, s1;
    if (*flag) {    // int64: dst e -> word 2e; src e -> word 2*Ecnt + 2e
        int4 dv = *(const int4*)&ew[4 * t];
        int4 sv = *(const int4*)&ew[2 * Ecnt + 4 * t];
        d0 = dv.x; d1 = dv.z; s0 = sv.x; s1 = sv.z;
    } else {        // int32
        int2 dv = *(const int2*)&ew[2 * t];
        int2 sv = *(const int2*)&ew[Ecnt + 2 * t];
        d0 = dv.x; d1 = dv.y; s0 = sv.x; s1 = sv.y;
    }
    int p0 = atomicAdd(&deg[d0], 1); if (p0 < CAP) slots[(d0 << 6) + p0] = s0;
    int p1 = atomicAdd(&deg[d1], 1); if (p1 < CAP) slots[(d1 << 6) + p1] = s1;
}

// ---------------------------------------------------------------------------
// aggb[node][c] = (d>0) ? max_{s in N(node)} xb[s][c] - xb[node][c] : 0
// One wave per node; neighbor ids broadcast via __shfl; lanes 0..47 own 4 ch.
__global__ __launch_bounds__(256) void agg_kernel(
    const int* __restrict__ deg, const int* __restrict__ slots,
    const __hip_bfloat16* __restrict__ xb, __hip_bfloat16* __restrict__ aggb) {
    int lane = threadIdx.x & 63, wave = threadIdx.x >> 6;
    int node = (blockIdx.x << 2) + wave;
    int d = deg[node]; if (d > CAP) d = CAP;
    int nbrval = 0;
    if (lane < d) nbrval = slots[(node << 6) + lane];
    const unsigned short* xbu = (const unsigned short*)xb;
    int act = lane < 48;
    int cb = lane * 4;
    float m0 = -INFINITY, m1 = -INFINITY, m2 = -INFINITY, m3 = -INFINITY;
    int k = 0;
    for (; k + 4 <= d; k += 4) {
        int s0 = __shfl(nbrval, k);
        int s1 = __shfl(nbrval, k + 1);
        int s2 = __shfl(nbrval, k + 2);
        int s3 = __shfl(nbrval, k + 3);
        if (act) {
            ushort4 v0 = *(const ushort4*)&xbu[s0 * Cch + cb];
            ushort4 v1 = *(const ushort4*)&xbu[s1 * Cch + cb];
            ushort4 v2 = *(const ushort4*)&xbu[s2 * Cch + cb];
            ushort4 v3 = *(const ushort4*)&xbu[s3 * Cch + cb];
            m0 = fmaxf(fmaxf(m0, b2f(v0.x)), fmaxf(fmaxf(b2f(v1.x), b2f(v2.x)), b2f(v3.x)));
            m1 = fmaxf(fmaxf(m1, b2f(v0.y)), fmaxf(fmaxf(b2f(v1.y), b2f(v2.y)), b2f(v3.y)));
            m2 = fmaxf(fmaxf(m2, b2f(v0.z)), fmaxf(fmaxf(b2f(v1.z), b2f(v2.z)), b2f(v3.z)));
            m3 = fmaxf(fmaxf(m3, b2f(v0.w)), fmaxf(fmaxf(b2f(v1.w), b2f(v2.w)), b2f(v3.w)));
        }
    }
    for (; k < d; k++) {
        int s = __shfl(nbrval, k);
        if (act) {
            ushort4 v = *(const ushort4*)&xbu[s * Cch + cb];
            m0 = fmaxf(m0, b2f(v.x)); m1 = fmaxf(m1, b2f(v.y));
            m2 = fmaxf(m2, b2f(v.z)); m3 = fmaxf(m3, b2f(v.w));
        }
    }
    if (act) {
        ushort4 xv = *(const ushort4*)&xbu[node * Cch + cb];
        ushort4 o4;
        o4.x = (d > 0) ? f2b(m0 - b2f(xv.x)) : 0;
        o4.y = (d > 0) ? f2b(m1 - b2f(xv.y)) : 0;
        o4.z = (d > 0) ? f2b(m2 - b2f(xv.z)) : 0;
        o4.w = (d > 0) ? f2b(m3 - b2f(xv.w)) : 0;
        *(ushort4*)&((unsigned short*)aggb)[node * Cch + cb] = o4;
    }
}

// ---------------------------------------------------------------------------
// out[b][o][n] = relu( Wx[o]·xb[node] + Wa[o]·agg[node] + bias[o] )
// 64(node) x 128(o) tile; grid (256,3); 4 waves (wm=node-half, wn=o-half).
// Per K-tile per thread: 3 gloads (A shared across both o-halves); per wave:
// 6 ds_read_b128 + 8 MFMA. K-chain order per acc tile identical to round 4
// -> bit-identical output.
__global__ __launch_bounds__(256) void gemm_kernel(
    const __hip_bfloat16* __restrict__ Xb, const __hip_bfloat16* __restrict__ Ab,
    const __hip_bfloat16* __restrict__ Wx, const __hip_bfloat16* __restrict__ Wa,
    const float* __restrict__ bias, float* __restrict__ out) {
    __shared__ short As[64 * 32];    // 4 KB  [node][k]
    __shared__ short Bs[128 * 32];   // 8 KB  [o][k]
    int t = threadIdx.x;
    int node0 = blockIdx.x * 64;
    int o0    = blockIdx.y * 128;
    int lane = t & 63, wave = t >> 6;
    int quad = lane >> 4, lrow = lane & 15;
    int wm = wave & 1, wn = wave >> 1;

    floatx4 acc[2][4] = {};
    int srow = t >> 2;             // 0..63 (4 threads per row)
    int koff = (t & 3) * 8;        // 0,8,16,24 elements within 32-k tile

    const __hip_bfloat16* Asrc[2] = {Xb, Ab};
    const __hip_bfloat16* Bsrc[2] = {Wx, Wa};

    for (int seg = 0; seg < 2; seg++) {
        const __hip_bfloat16* a_g = Asrc[seg] + (size_t)(node0 + srow) * Cch + koff;
        const __hip_bfloat16* b_g = Bsrc[seg] + (size_t)(o0 + srow) * Cch + koff;
        for (int kt = 0; kt < Cch; kt += 32) {
            __syncthreads();
            gload_lds16(a_g + kt,                    &As[t * 8]);
            gload_lds16(b_g + kt,                    &Bs[t * 8]);
            gload_lds16(b_g + kt + (size_t)64 * Cch, &Bs[2048 + t * 8]);
            __syncthreads();
            short8 af[2], bf[4];
#pragma unroll
            for (int i = 0; i < 2; i++)
                af[i] = *(const short8*)&As[(wm * 32 + i * 16 + lrow) * 32 + quad * 8];
#pragma unroll
            for (int j = 0; j < 4; j++)
                bf[j] = *(const short8*)&Bs[(wn * 64 + j * 16 + lrow) * 32 + quad * 8];
#pragma unroll
            for (int i = 0; i < 2; i++)
#pragma unroll
                for (int j = 0; j < 4; j++)
                    acc[i][j] = __builtin_amdgcn_mfma_f32_16x16x32_bf16(bf[j], af[i], acc[i][j], 0, 0, 0);
        }
    }

    // D layout: col(lane&15)=node, row(quad*4+r)=o
#pragma unroll
    for (int i = 0; i < 2; i++) {
        int node = node0 + wm * 32 + i * 16 + lrow;
        int b = node >> 12, n = node & 4095;
#pragma unroll
        for (int j = 0; j < 4; j++) {
            int ob = o0 + wn * 64 + j * 16 + quad * 4;
#pragma unroll
            for (int r = 0; r < 4; r++) {
                int o = ob + r;
                float v = acc[i][j][r] + bias[o];
                out[((size_t)(b * COUT + o)) * Nn + n] = fmaxf(v, 0.0f);
            }
        }
    }
}

// ---------------------------------------------------------------------------
extern "C" void kernel_launch(void* const* d_in, const int* in_sizes, int n_in,
                              void* d_out, int out_size, void* d_ws, size_t ws_size,
                              hipStream_t stream) {
    const float* x    = (const float*)d_in[0];
    const int*   ew   = (const int*)d_in[1];
    const float* W    = (const float*)d_in[2];
    const float* bias = (const float*)d_in[3];
    float* out        = (float*)d_out;

    char* ws = (char*)d_ws;
    __hip_bfloat16* xb   = (__hip_bfloat16*)ws;                       // 6291456 B
    __hip_bfloat16* aggb = (__hip_bfloat16*)(ws + 6291456);           // 6291456 B
    __hip_bfloat16* Wx   = (__hip_bfloat16*)(ws + 12582912);          // 147456 B
    __hip_bfloat16* Wa   = (__hip_bfloat16*)(ws + 12730368);          // 147456 B
    int* deg   = (int*)(ws + 12877824);                               // 65536 B
    int* slots = (int*)(ws + 12943360);                               // 4194304 B
    int* flag  = (int*)(ws + 17137664);                               // 4 B

    prep_kernel<<<3425, 256, 0, stream>>>(x, (const unsigned int*)ew, W, xb, Wx, Wa, deg, flag);
    fill_kernel<<<Ecnt / 512, 256, 0, stream>>>(ew, flag, deg, slots);
    agg_kernel<<<BN / 4, 256, 0, stream>>>(deg, slots, xb, aggb);
    gemm_kernel<<<dim3(BN / 64, COUT / 128), 256, 0, stream>>>(xb, aggb, Wx, Wa, bias, out);
}